// Round 9
// baseline (139.236 us; speedup 1.0000x reference)
//
#include <hip/hip_runtime.h>

typedef __attribute__((ext_vector_type(8))) short bf16x8;
typedef __attribute__((ext_vector_type(4))) float f32x4;
typedef __attribute__((ext_vector_type(4))) unsigned short us4;

#define NBATCH 64
#define NFEAT  64
#define NSITES 1024
#define NSYMM  1024
#define NINF   4
#define XSTR   1160         // LDS elems per x-copy slot (2320 B; 580 dw % 32 = 4 -> bank spread)
#define XWIN   2304         // elems per shifted-copy window in xshift (covers k0<=960 + 1152)

static __device__ __forceinline__ unsigned short f2bf(float f) {
  union { float f; unsigned int u; } v; v.f = f;
  unsigned int u = v.u;
  return (unsigned short)((u + 0x7fffu + ((u >> 16) & 1u)) >> 16);  // RNE
}

#define GLDS16(g, l) \
  __builtin_amdgcn_global_load_lds((const __attribute__((address_space(1))) unsigned int*)(g), \
                                   (__attribute__((address_space(3))) unsigned int*)(l), 16, 0, 0)
#define GLDS4(g, l) \
  __builtin_amdgcn_global_load_lds((const __attribute__((address_space(1))) unsigned int*)(g), \
                                   (__attribute__((address_space(3))) unsigned int*)(l), 4, 0, 0)

// ---------------- fused prepass ---------------------------------------------------------
// blocks [0,128):    w -> bf16 REGISTER-FRAGMENT blobs: for step=(j*8+lt), wave wv, lane,
//                    mf: 8 elems w[m = mf*16 + (lane&15)][l = lt*128 + wv*32 + ((lane>>4)<<3) + s]
//                    at wprep[(((step*4+wv)*64+lane)*4+mf)*8 + s].
// blocks [128,2176): x -> bf16, 8 shifted copies, XWIN-wide window:
//                    xshift[i][j][c][p] = bf16(x[i][j][(p+c) & 1023]), p in [0,XWIN)
__global__ void prep_all(const float* __restrict__ x, const float* __restrict__ ker,
                         unsigned short* __restrict__ wprep, unsigned short* __restrict__ xshift) {
  int b = blockIdx.x;
  if (b < 128) {
    int t = b * 256 + threadIdx.x;          // 0..32767, one 16B blob each
    int mf = t & 3, lane = (t >> 2) & 63, wvq = (t >> 8) & 3, step = t >> 10;
    int j = step >> 3, lt = step & 7;
    int m = mf * 16 + (lane & 15);
    int l = lt * 128 + wvq * 32 + ((lane >> 4) << 3);
    const float* kp = &ker[(m * NINF + j) * NSITES + l];
    const float4 v0 = *(const float4*)kp;
    const float4 v1 = *(const float4*)(kp + 4);
    us4 h0, h1;
    h0.x = f2bf(v0.x); h0.y = f2bf(v0.y); h0.z = f2bf(v0.z); h0.w = f2bf(v0.w);
    h1.x = f2bf(v1.x); h1.y = f2bf(v1.y); h1.z = f2bf(v1.z); h1.w = f2bf(v1.w);
    *(us4*)&wprep[t * 8]     = h0;
    *(us4*)&wprep[t * 8 + 4] = h1;
  } else {
    int bb = b - 128;
    int ij = bb >> 3, cc = bb & 7;
    const float* xr = x + ij * NSITES;
    unsigned short* dst = xshift + (size_t)(ij * 8 + cc) * XWIN;
    #pragma unroll
    for (int r = 0; r < 3; ++r) {
      int u = r * 256 + threadIdx.x;
      if (u < XWIN / 4) {
        int p = u << 2;
        us4 h;
        h.x = f2bf(xr[(p + cc)     & 1023]);
        h.y = f2bf(xr[(p + cc + 1) & 1023]);
        h.z = f2bf(xr[(p + cc + 2) & 1023]);
        h.w = f2bf(xr[(p + cc + 3) & 1023]);
        *(us4*)&dst[p] = h;
      }
    }
  }
}

// ---------------- main kernel: k64 blocks, 4 blocks/CU, barrier-free steady state -------
// Grid 1024 = i(64) x ktile(16). Wave wv owns l-subchunk wv*32 of each 128-l step tile and
// computes the full m64 x k64 block tile as an l-partial (acc[4][4] = 64 VGPR). A-frags
// stream global->VGPR double-buffered; B-frags from xc LDS (stable per j). Cross-wave
// l-reduction via LDS in the epilogue.
__global__ __launch_bounds__(256, 4)
void dense_symm_main(const unsigned short* __restrict__ wprep,
                     const unsigned short* __restrict__ xshift,
                     const float* __restrict__ bias,
                     float* __restrict__ out)
{
  __shared__ unsigned short xc[8 * XSTR];      // 18.1 KB, 8 shifted x copies (per j)
  __shared__ float red[4 * 4 * 64 * 4];        // 16 KB, epilogue reduction buffer

  const int tid  = threadIdx.x;   // 0..255
  const int lane = tid & 63;
  const int wv   = tid >> 6;      // 0..3; wave owns l-subchunk wv*32
  const int wg   = blockIdx.x;
  const int i    = wg >> 4;
  const int k0   = (wg & 15) << 6;

  f32x4 acc[4][4];                // [mf][f] — m64 x k64 l-partial
  #pragma unroll
  for (int mf = 0; mf < 4; ++mf)
    #pragma unroll
    for (int f = 0; f < 4; ++f) acc[mf][f] = (f32x4)0.f;

  const int akk = (lane >> 4) << 3;               // l-offset within the 32-l chunk
  const int c   = lane & 7;                       // which shifted copy
  const int pb  = akk + (((lane >> 3) & 1) << 3); // B addr: p = l0 + f*16 + pb (+s)

  auto stage_x_chunk = [&](int jj, int c3) {      // c3 in [0,24): copy=c3/3, part=c3%3
    int cc = c3 / 3, part = c3 % 3;
    const char* src = (const char*)(xshift + (size_t)((i * 4 + jj) * 8 + cc) * XWIN + k0);
    char* dst = (char*)&xc[0] + cc * (XSTR * 2);
    if (part < 2) GLDS16(src + part * 1024 + lane * 16, dst + part * 1024);
    else          GLDS4(src + 2048 + lane * 4, dst + 2048);
  };

  // per-(step,wv) A blob base: elem offset ((step*4+wv)*64+lane)*32 + mf*8
  const unsigned short* wbase = wprep + (((size_t)wv * 64 + lane) << 5);
  auto loadA = [&](bf16x8* dst, int s) {
    const unsigned short* p = wbase + ((size_t)s << 13);
    #pragma unroll
    for (int mf = 0; mf < 4; ++mf) dst[mf] = *(const bf16x8*)(p + mf * 8);
  };

  // --- prologue: xc(j=0) + A(step 0) ---
  for (int r = 0; r < 6; ++r) stage_x_chunk(0, wv * 6 + r);
  bf16x8 a0[4], a1[4];
  loadA(a0, 0);
  __syncthreads();

  for (int j = 0; j < 4; ++j) {
    if (j > 0) {
      __syncthreads();                            // all xc reads for j-1 done
      for (int r = 0; r < 6; ++r) stage_x_chunk(j, wv * 6 + r);
      __syncthreads();                            // refill visible (vmcnt drained)
    }
    const unsigned short* xcc = &xc[c * XSTR];
    #pragma unroll
    for (int lt = 0; lt < 8; ++lt) {              // full unroll -> a0/a1 select is static
      const int step = j * 8 + lt;
      const bf16x8* acur = (lt & 1) ? a1 : a0;
      bf16x8*       anxt = (lt & 1) ? a0 : a1;
      if (step < 31) loadA(anxt, step + 1);       // prefetch next step's A into regs
      const int l0 = lt * 128 + wv * 32;
      #pragma unroll
      for (int f = 0; f < 4; ++f) {
        bf16x8 bfr = *(const bf16x8*)&xcc[l0 + f * 16 + pb];
        #pragma unroll
        for (int mf = 0; mf < 4; ++mf)
          acc[mf][f] = __builtin_amdgcn_mfma_f32_16x16x32_bf16(acur[mf], bfr, acc[mf][f], 0, 0, 0);
      }
    }
  }

  // --- epilogue: cross-wave l-reduction via LDS; wave wv finalizes f = wv -------------
  // C/D layout col=lane&15, row=(lane>>4)*4+reg [m89]; lane-aligned across waves.
  const int col = lane & 15;
  const int rb  = (lane >> 4) << 2;
  #pragma unroll
  for (int mf = 0; mf < 4; ++mf) {
    __syncthreads();                              // prev reads / final compute done
    #pragma unroll
    for (int f = 0; f < 4; ++f)
      *(f32x4*)&red[(((wv << 2) + f) << 6 | lane) << 2] = acc[mf][f];
    __syncthreads();
    {
      const int f = wv;                           // one k16 stripe per wave
      f32x4 s0 = *(const f32x4*)&red[((0 * 4 + f) << 6 | lane) << 2];
      f32x4 s1 = *(const f32x4*)&red[((1 * 4 + f) << 6 | lane) << 2];
      f32x4 s2 = *(const f32x4*)&red[((2 * 4 + f) << 6 | lane) << 2];
      f32x4 s3 = *(const f32x4*)&red[((3 * 4 + f) << 6 | lane) << 2];
      #pragma unroll
      for (int r = 0; r < 4; ++r) {
        int m = mf * 16 + rb + r;
        int k = k0 + f * 16 + col;
        out[(i * NFEAT + m) * NSYMM + k] = s0[r] + s1[r] + s2[r] + s3[r] + bias[m];
      }
    }
  }
}

// ---------------- fallback (round-1 kernel, used only if ws_size too small) -------------
#define FB_BN 128
#define BL 128
#define WSTR 136
__global__ __launch_bounds__(256, 2)
void dense_symm_kernel(const float* __restrict__ x,
                       const float* __restrict__ ker,
                       const float* __restrict__ bias,
                       float* __restrict__ out)
{
  __shared__ unsigned short xcp[8 * XSTR];
  __shared__ unsigned short wS[64 * WSTR];
  const int tid  = threadIdx.x;
  const int lane = tid & 63;
  const int wv   = tid >> 6;
  const int wg   = blockIdx.x;
  const int i    = wg >> 3;
  const int k0   = (wg & 7) * FB_BN;
  f32x4 acc[4][2];
  for (int mf = 0; mf < 4; ++mf)
    for (int f = 0; f < 2; ++f) acc[mf][f] = (f32x4)0.f;
  const int arow   = lane & 15;
  const int akk    = (lane >> 4) << 3;
  const int c      = lane & 7;
  const int pbase0 = wv * 32 + akk + (((lane >> 3) & 1) << 3);
  for (int j = 0; j < NINF; ++j) {
    __syncthreads();
    const float* xrow = x + (i * NINF + j) * NSITES;
    for (int cc = 0; cc < 8; ++cc)
      for (int p = tid; p < NSITES + FB_BN; p += 256)
        xcp[cc * XSTR + p] = f2bf(xrow[(p + cc + k0) & (NSITES - 1)]);
    for (int lt = 0; lt < NSITES / BL; ++lt) {
      __syncthreads();
      for (int u = 0; u < 8; ++u) {
        int q = u * 256 + tid;
        int m = q >> 5, c4 = q & 31;
        const float4 v = *(const float4*)&ker[(m * NINF + j) * NSITES + lt * BL + (c4 << 2)];
        us4 h; h.x = f2bf(v.x); h.y = f2bf(v.y); h.z = f2bf(v.z); h.w = f2bf(v.w);
        *(us4*)&wS[m * WSTR + (c4 << 2)] = h;
      }
      __syncthreads();
      for (int ks = 0; ks < BL / 32; ++ks) {
        bf16x8 afr[4];
        for (int mf = 0; mf < 4; ++mf)
          afr[mf] = *(const bf16x8*)&wS[(mf * 16 + arow) * WSTR + ks * 32 + akk];
        const int l0 = lt * BL + ks * 32;
        for (int f = 0; f < 2; ++f) {
          bf16x8 bfr = *(const bf16x8*)&xcp[c * XSTR + l0 + f * 16 + pbase0];
          for (int mf = 0; mf < 4; ++mf)
            acc[mf][f] = __builtin_amdgcn_mfma_f32_16x16x32_bf16(afr[mf], bfr, acc[mf][f], 0, 0, 0);
        }
      }
    }
  }
  const int col = lane & 15;
  const int rb  = (lane >> 4) << 2;
  for (int mf = 0; mf < 4; ++mf)
    for (int f = 0; f < 2; ++f)
      for (int r = 0; r < 4; ++r) {
        int m = mf * 16 + rb + r;
        int k = k0 + wv * 32 + f * 16 + col;
        out[(i * NFEAT + m) * NSYMM + k] = acc[mf][f][r] + bias[m];
      }
}

extern "C" void kernel_launch(void* const* d_in, const int* in_sizes, int n_in,
                              void* d_out, int out_size, void* d_ws, size_t ws_size,
                              hipStream_t stream) {
  const float* x    = (const float*)d_in[0];
  // d_in[1] = symm (cyclic translations by construction) — unused
  const float* ker  = (const float*)d_in[2];
  const float* bias = (const float*)d_in[3];
  float* out = (float*)d_out;

  const size_t w_elems = 4u * 8u * 64u * 128u;            // 262144 (512 KB)
  const size_t x_elems = (size_t)256 * 8 * XWIN;          // 4718592 (9.4 MB)
  if (ws_size >= (w_elems + x_elems) * sizeof(unsigned short)) {
    unsigned short* wprep  = (unsigned short*)d_ws;
    unsigned short* xshift = wprep + w_elems;
    prep_all<<<dim3(2176), dim3(256), 0, stream>>>(x, ker, wprep, xshift);
    dense_symm_main<<<dim3(1024), dim3(256), 0, stream>>>(wprep, xshift, bias, out);
  } else {
    dense_symm_kernel<<<dim3(512), dim3(256), 0, stream>>>(x, ker, bias, out);
  }
}

// Round 10
// 98.661 us; speedup vs baseline: 1.4113x; 1.4113x over previous
//
#include <hip/hip_runtime.h>

typedef __attribute__((ext_vector_type(8))) short bf16x8;
typedef __attribute__((ext_vector_type(4))) float f32x4;
typedef __attribute__((ext_vector_type(4))) unsigned short us4;

#define NBATCH 64
#define NFEAT  64
#define NSITES 1024
#define NSYMM  1024
#define NINF   4
#define BN     128          // k-tile per workgroup
#define XSTR   1160         // LDS elems per x-copy slot (2320 B)

static __device__ __forceinline__ unsigned short f2bf(float f) {
  union { float f; unsigned int u; } v; v.f = f;
  unsigned int u = v.u;
  return (unsigned short)((u + 0x7fffu + ((u >> 16) & 1u)) >> 16);  // RNE
}

#define GLDS16(g, l) \
  __builtin_amdgcn_global_load_lds((const __attribute__((address_space(1))) unsigned int*)(g), \
                                   (__attribute__((address_space(3))) unsigned int*)(l), 16, 0, 0)
#define GLDS4(g, l) \
  __builtin_amdgcn_global_load_lds((const __attribute__((address_space(1))) unsigned int*)(g), \
                                   (__attribute__((address_space(3))) unsigned int*)(l), 4, 0, 0)

// ---------------- fused prepass (identical to round 7) ---------------------------------
// blocks [0,128):    w -> bf16 REGISTER-FRAGMENT blobs: for step=(j*8+lt), wave wv, lane,
//                    mf: 8 elems w[m = mf*16 + (lane&15)][l = lt*128 + wv*32 + ((lane>>4)<<3) + s]
//                    at wprep[(((step*4+wv)*64+lane)*4+mf)*8 + s].
// blocks [128,2176): x -> bf16, 8 shifted copies, 2048-wide window:
//                    xshift[i][j][c][p] = bf16(x[i][j][(p+c) & 1023])
__global__ void prep_all(const float* __restrict__ x, const float* __restrict__ ker,
                         unsigned short* __restrict__ wprep, unsigned short* __restrict__ xshift) {
  int b = blockIdx.x;
  if (b < 128) {
    int t = b * 256 + threadIdx.x;          // 0..32767, one 16B blob each
    int mf = t & 3, lane = (t >> 2) & 63, wvq = (t >> 8) & 3, step = t >> 10;
    int j = step >> 3, lt = step & 7;
    int m = mf * 16 + (lane & 15);
    int l = lt * 128 + wvq * 32 + ((lane >> 4) << 3);
    const float* kp = &ker[(m * NINF + j) * NSITES + l];
    const float4 v0 = *(const float4*)kp;
    const float4 v1 = *(const float4*)(kp + 4);
    us4 h0, h1;
    h0.x = f2bf(v0.x); h0.y = f2bf(v0.y); h0.z = f2bf(v0.z); h0.w = f2bf(v0.w);
    h1.x = f2bf(v1.x); h1.y = f2bf(v1.y); h1.z = f2bf(v1.z); h1.w = f2bf(v1.w);
    *(us4*)&wprep[t * 8]     = h0;
    *(us4*)&wprep[t * 8 + 4] = h1;
  } else {
    int bb = b - 128;
    int ij = bb >> 3, cc = bb & 7;
    const float* xr = x + ij * NSITES;
    unsigned short* dst = xshift + (size_t)(ij * 8 + cc) * 2048;
    #pragma unroll
    for (int r = 0; r < 2; ++r) {
      int p = (r * 256 + threadIdx.x) << 2;
      us4 h;
      h.x = f2bf(xr[(p + cc)     & 1023]);
      h.y = f2bf(xr[(p + cc + 1) & 1023]);
      h.z = f2bf(xr[(p + cc + 2) & 1023]);
      h.w = f2bf(xr[(p + cc + 3) & 1023]);
      *(us4*)&dst[p] = h;
    }
  }
}

// ---------------- main kernel: r7 skeleton + xc-dbuf + hoisted B reads + setprio --------
// 512 blocks (2/CU), 4 waves; wave wv owns l-subchunk wv*32 of each 128-l step tile,
// computes the full m64 x k128 tile as an l-partial (acc[4][8]). A-frags stream
// global->VGPR double-buffered. xc double-buffered: stage j+1 issued at start of j's
// compute; ONE barrier per j-boundary. Cross-wave l-reduction in epilogue (red overlays xc).
__global__ __launch_bounds__(256, 2)
void dense_symm_main(const unsigned short* __restrict__ wprep,
                     const unsigned short* __restrict__ xshift,
                     const float* __restrict__ bias,
                     float* __restrict__ out)
{
  __shared__ unsigned short xc2[2][8 * XSTR];  // 2 x 18.1 KB, double-buffered x copies
  // epilogue reduction buffer overlays xc2 (32 KB < 36.3 KB) — xc dead by then
  float* red = (float*)&xc2[0][0];

  const int tid  = threadIdx.x;   // 0..255
  const int lane = tid & 63;
  const int wv   = tid >> 6;      // 0..3; wave owns l-subchunk wv*32
  const int wg   = blockIdx.x;
  const int i    = wg >> 3;
  const int k0   = (wg & 7) * BN;

  f32x4 acc[4][8];                // [mf][f] — m64 x k128 l-partial
  #pragma unroll
  for (int mf = 0; mf < 4; ++mf)
    #pragma unroll
    for (int f = 0; f < 8; ++f) acc[mf][f] = (f32x4)0.f;

  const int akk = (lane >> 4) << 3;               // l-offset within the 32-l chunk
  const int c   = lane & 7;                       // which shifted copy
  const int pb  = akk + (((lane >> 3) & 1) << 3); // B addr: p = l0 + f*16 + pb (+s)

  auto stage_x_chunk = [&](int buf, int jj, int c3) {  // c3 in [0,24): copy=c3/3, part=c3%3
    int cc = c3 / 3, part = c3 % 3;
    const char* src = (const char*)(xshift + (((i * 4 + jj) * 8 + cc) << 11) + k0);
    char* dst = (char*)&xc2[buf][0] + cc * (XSTR * 2);
    if (part < 2) GLDS16(src + part * 1024 + lane * 16, dst + part * 1024);
    else          GLDS4(src + 2048 + lane * 4, dst + 2048);
  };

  // per-(step,wv) A blob base: elem offset ((step*4+wv)*64+lane)*32 + mf*8
  const unsigned short* wbase = wprep + (((size_t)wv * 64 + lane) << 5);
  auto loadA = [&](bf16x8* dst, int s) {
    const unsigned short* p = wbase + ((size_t)s << 13);
    #pragma unroll
    for (int mf = 0; mf < 4; ++mf) dst[mf] = *(const bf16x8*)(p + mf * 8);
  };

  // --- prologue: xc buf0 (j=0) + A(step 0) ---
  for (int r = 0; r < 6; ++r) stage_x_chunk(0, 0, wv * 6 + r);
  bf16x8 a0[4], a1[4];
  loadA(a0, 0);
  __syncthreads();                                // drains vmcnt(0): buf0 + a0 ready

  #pragma unroll
  for (int j = 0; j < 4; ++j) {
    // issue next j's xc stage into the other buffer (overlaps this j's compute)
    if (j < 3)
      for (int r = 0; r < 6; ++r) stage_x_chunk((j + 1) & 1, j + 1, wv * 6 + r);

    const unsigned short* xcc = &xc2[j & 1][c * XSTR];
    #pragma unroll
    for (int lt = 0; lt < 8; ++lt) {              // full unroll -> a0/a1 select is static
      const int step = j * 8 + lt;
      const bf16x8* acur = (lt & 1) ? a1 : a0;
      bf16x8*       anxt = (lt & 1) ? a0 : a1;
      if (step < 31) loadA(anxt, step + 1);       // prefetch next step's A into regs

      const int l0 = lt * 128 + wv * 32;
      bf16x8 bfr[8];                              // hoist ALL B reads before MFMA cluster
      #pragma unroll
      for (int f = 0; f < 8; ++f)
        bfr[f] = *(const bf16x8*)&xcc[l0 + f * 16 + pb];

      __builtin_amdgcn_s_setprio(1);
      #pragma unroll
      for (int f = 0; f < 8; ++f)
        #pragma unroll
        for (int mf = 0; mf < 4; ++mf)
          acc[mf][f] = __builtin_amdgcn_mfma_f32_16x16x32_bf16(acur[mf], bfr[f], acc[mf][f], 0, 0, 0);
      __builtin_amdgcn_s_setprio(0);
    }
    __syncthreads();                              // j-boundary: drain stage, swap buffers
  }

  // --- epilogue: cross-wave l-reduction via LDS (red overlays xc2) ---------------------
  // C/D layout col=lane&15, row=(lane>>4)*4+reg [m89]; lane-aligned across waves.
  const int col = lane & 15;
  const int rb  = (lane >> 4) << 2;
  #pragma unroll
  for (int mf = 0; mf < 4; ++mf) {
    if (mf > 0) __syncthreads();                  // prev iter's reads done
    #pragma unroll
    for (int f = 0; f < 8; ++f)
      *(f32x4*)&red[(((wv << 3) + f) << 6 | lane) << 2] = acc[mf][f];
    __syncthreads();
    #pragma unroll
    for (int fo = 0; fo < 2; ++fo) {              // wave wv reduces f-range [2*wv, 2*wv+2)
      int f = (wv << 1) + fo;
      f32x4 s0 = *(const f32x4*)&red[((0 * 8 + f) << 6 | lane) << 2];
      f32x4 s1 = *(const f32x4*)&red[((1 * 8 + f) << 6 | lane) << 2];
      f32x4 s2 = *(const f32x4*)&red[((2 * 8 + f) << 6 | lane) << 2];
      f32x4 s3 = *(const f32x4*)&red[((3 * 8 + f) << 6 | lane) << 2];
      #pragma unroll
      for (int r = 0; r < 4; ++r) {
        int m = mf * 16 + rb + r;
        int k = k0 + f * 16 + col;
        out[(i * NFEAT + m) * NSYMM + k] = s0[r] + s1[r] + s2[r] + s3[r] + bias[m];
      }
    }
  }
}

// ---------------- fallback (round-1 kernel, used only if ws_size too small) -------------
#define BL 128
#define WSTR 136
__global__ __launch_bounds__(256, 2)
void dense_symm_kernel(const float* __restrict__ x,
                       const float* __restrict__ ker,
                       const float* __restrict__ bias,
                       float* __restrict__ out)
{
  __shared__ unsigned short xcp[8 * XSTR];
  __shared__ unsigned short wS[64 * WSTR];
  const int tid  = threadIdx.x;
  const int lane = tid & 63;
  const int wv   = tid >> 6;
  const int wg   = blockIdx.x;
  const int i    = wg >> 3;
  const int k0   = (wg & 7) * BN;
  f32x4 acc[4][2];
  for (int mf = 0; mf < 4; ++mf)
    for (int f = 0; f < 2; ++f) acc[mf][f] = (f32x4)0.f;
  const int arow   = lane & 15;
  const int akk    = (lane >> 4) << 3;
  const int c      = lane & 7;
  const int pbase0 = wv * 32 + akk + (((lane >> 3) & 1) << 3);
  for (int j = 0; j < NINF; ++j) {
    __syncthreads();
    const float* xrow = x + (i * NINF + j) * NSITES;
    for (int cc = 0; cc < 8; ++cc)
      for (int p = tid; p < NSITES + BN; p += 256)
        xcp[cc * XSTR + p] = f2bf(xrow[(p + cc + k0) & (NSITES - 1)]);
    for (int lt = 0; lt < NSITES / BL; ++lt) {
      __syncthreads();
      for (int u = 0; u < 8; ++u) {
        int q = u * 256 + tid;
        int m = q >> 5, c4 = q & 31;
        const float4 v = *(const float4*)&ker[(m * NINF + j) * NSITES + lt * BL + (c4 << 2)];
        us4 h; h.x = f2bf(v.x); h.y = f2bf(v.y); h.z = f2bf(v.z); h.w = f2bf(v.w);
        *(us4*)&wS[m * WSTR + (c4 << 2)] = h;
      }
      __syncthreads();
      for (int ks = 0; ks < BL / 32; ++ks) {
        bf16x8 afr[4];
        for (int mf = 0; mf < 4; ++mf)
          afr[mf] = *(const bf16x8*)&wS[(mf * 16 + arow) * WSTR + ks * 32 + akk];
        const int l0 = lt * BL + ks * 32;
        for (int f = 0; f < 2; ++f) {
          bf16x8 bfr = *(const bf16x8*)&xcp[c * XSTR + l0 + f * 16 + pbase0];
          for (int mf = 0; mf < 4; ++mf)
            acc[mf][f] = __builtin_amdgcn_mfma_f32_16x16x32_bf16(afr[mf], bfr, acc[mf][f], 0, 0, 0);
        }
      }
    }
  }
  const int col = lane & 15;
  const int rb  = (lane >> 4) << 2;
  for (int mf = 0; mf < 4; ++mf)
    for (int f = 0; f < 2; ++f)
      for (int r = 0; r < 4; ++r) {
        int m = mf * 16 + rb + r;
        int k = k0 + wv * 32 + f * 16 + col;
        out[(i * NFEAT + m) * NSYMM + k] = acc[mf][f][r] + bias[m];
      }
}

extern "C" void kernel_launch(void* const* d_in, const int* in_sizes, int n_in,
                              void* d_out, int out_size, void* d_ws, size_t ws_size,
                              hipStream_t stream) {
  const float* x    = (const float*)d_in[0];
  // d_in[1] = symm (cyclic translations by construction) — unused
  const float* ker  = (const float*)d_in[2];
  const float* bias = (const float*)d_in[3];
  float* out = (float*)d_out;

  const size_t w_elems = 4u * 8u * 64u * 128u;            // 262144 (512 KB)
  const size_t x_elems = 64u * 4u * 8u * 2048u;           // 4194304 (8 MB)
  if (ws_size >= (w_elems + x_elems) * sizeof(unsigned short)) {
    unsigned short* wprep  = (unsigned short*)d_ws;
    unsigned short* xshift = wprep + w_elems;
    prep_all<<<dim3(2176), dim3(256), 0, stream>>>(x, ker, wprep, xshift);
    dense_symm_main<<<dim3(512), dim3(256), 0, stream>>>(wprep, xshift, bias, out);
  } else {
    dense_symm_kernel<<<dim3(512), dim3(256), 0, stream>>>(x, ker, bias, out);
  }
}